// Round 3
// baseline (1471.172 us; speedup 1.0000x reference)
//
#include <hip/hip_runtime.h>

// ---------------------------------------------------------------------------
// InterpretableFusion v3: query = X@Wq^T + bq ; keys_m = L_m@Wk[m]^T + bk[m]
// scores = q.k/sqrt(D); weights = softmax_m; fused = sum_m w_m L_m
// N=50000, M=4, D=512. fp32 in/out, bf16 MFMA compute.
//
// Single kernel (no d_ws: round-1 post-timing divergence consistent with
// cross-XCD L2 non-coherence between graph nodes).
// BN=128 rows/block, 1024 threads (16 waves) -> halves per-block W traffic
// vs BN=64 (total 391 x 5.25MB = 2.05GB of L2-reads) and 2x latency hiding.
// Two-pass: pass1 = scores only (kacc folded j-half-sequentially, 32 regs);
// pass2 = fused from HBM fp32 latents in own-row layout, 128B-coalesced
// nt float4 stores (fixes round-2's 2.65x write amplification).
// ---------------------------------------------------------------------------

typedef __bf16 bf16x8 __attribute__((ext_vector_type(8)));
typedef __bf16 bf16x4 __attribute__((ext_vector_type(4)));
typedef float  f32x4  __attribute__((ext_vector_type(4)));

#define NTOK 50000
#define DDIM 512
#define NMOD 4
#define BN   128
#define NTHR 1024
#define NBLK ((NTOK + BN - 1) / BN)   // 391

// row stride 1024B (512 bf16); XOR byte bits 4-6 with row&7 (guide §6 G4)
#define SWZ(r, b) ((((r) * 1024) + (b)) ^ (((r) & 7) << 4))

__global__ __launch_bounds__(NTHR, 1) void fusion_kernel(
    const float* __restrict__ gnn, const float* __restrict__ lat,
    const float* __restrict__ Wq, const float* __restrict__ bq,
    const float* __restrict__ Wk, const float* __restrict__ bk,
    float* __restrict__ out)
{
    __shared__ __bf16 tile[BN * DDIM];      // 128 KiB (X, then L_m)
    __shared__ float  s_part[4][BN];        // 2 KiB
    __shared__ float  e_save[BN][NMOD];     // 2 KiB

    const int tid  = threadIdx.x;
    const int lane = tid & 63;
    const int wv   = tid >> 6;        // 0..15
    const int wr   = wv >> 2;         // row-group: rows [wr*32, +32)
    const int wc   = wv & 3;          // col-group: cols [wc*128, +128)
    const int g    = (lane >> 4) & 3;
    const int c    = lane & 15;
    const int row0 = blockIdx.x * BN;
    const int vrows = (NTOK - row0 < BN) ? (NTOK - row0) : BN;

    const char* lc = (const char*)tile;

    // ---- stage [vrows][512] fp32 -> swizzled bf16 tile (zero-pad dead rows)
    auto stage = [&](const float* src, int rsF) {
        #pragma unroll
        for (int bat = 0; bat < 2; ++bat) {
            f32x4 tmp[8];
            #pragma unroll
            for (int i = 0; i < 8; ++i) {
                int f4 = (bat * 8 + i) * NTHR + tid;   // 0..16383
                int r = f4 >> 7, c4 = f4 & 127;
                tmp[i] = (r < vrows)
                    ? __builtin_nontemporal_load(
                          (const f32x4*)(src + (size_t)r * rsF + c4 * 4))
                    : (f32x4){0.f, 0.f, 0.f, 0.f};
            }
            #pragma unroll
            for (int i = 0; i < 8; ++i) {
                int f4 = (bat * 8 + i) * NTHR + tid;
                int r = f4 >> 7, c4 = f4 & 127;
                bf16x4 o;
                o[0] = (__bf16)tmp[i][0]; o[1] = (__bf16)tmp[i][1];
                o[2] = (__bf16)tmp[i][2]; o[3] = (__bf16)tmp[i][3];
                *(bf16x4*)((char*)tile + SWZ(r, c4 * 8)) = o;
            }
        }
    };

    // ---- half-GEMM: out cols [wc*128+jh*64, +64), rows [wr*32,+32), full K
    auto gemm_half = [&](const float* W, int jh, f32x4 (&kc)[2][4]) {
        #pragma unroll
        for (int rt = 0; rt < 2; ++rt)
            #pragma unroll
            for (int j = 0; j < 4; ++j) kc[rt][j] = (f32x4){0.f, 0.f, 0.f, 0.f};
        for (int k0 = 0; k0 < DDIM; k0 += 32) {
            bf16x8 a[2], b[4];
            const int kb = k0 * 2 + g * 16;
            #pragma unroll
            for (int rt = 0; rt < 2; ++rt)
                a[rt] = *(const bf16x8*)(lc + SWZ(wr * 32 + rt * 16 + c, kb));
            #pragma unroll
            for (int j = 0; j < 4; ++j) {
                const float* wp = W + (size_t)(wc * 128 + jh * 64 + j * 16 + c) * DDIM
                                    + k0 + g * 8;
                f32x4 v0 = *(const f32x4*)wp;
                f32x4 v1 = *(const f32x4*)(wp + 4);
                bf16x8 t;
                t[0] = (__bf16)v0[0]; t[1] = (__bf16)v0[1];
                t[2] = (__bf16)v0[2]; t[3] = (__bf16)v0[3];
                t[4] = (__bf16)v1[0]; t[5] = (__bf16)v1[1];
                t[6] = (__bf16)v1[2]; t[7] = (__bf16)v1[3];
                b[j] = t;
            }
            #pragma unroll
            for (int rt = 0; rt < 2; ++rt)
                #pragma unroll
                for (int j = 0; j < 4; ++j)
                    kc[rt][j] = __builtin_amdgcn_mfma_f32_16x16x32_bf16(
                        a[rt], b[j], kc[rt][j], 0, 0, 0);
        }
    };

    // ================= phase 1: Q = X@Wq^T + bq (packed bf16) =================
    stage(gnn + (size_t)row0 * DDIM, DDIM);
    __syncthreads();

    bf16x4 qbf[2][8];
    #pragma unroll
    for (int jh = 0; jh < 2; ++jh) {
        f32x4 kc[2][4];
        gemm_half(Wq, jh, kc);
        #pragma unroll
        for (int j = 0; j < 4; ++j) {
            float bqv = bq[wc * 128 + jh * 64 + j * 16 + c];
            #pragma unroll
            for (int rt = 0; rt < 2; ++rt)
                #pragma unroll
                for (int reg = 0; reg < 4; ++reg)
                    qbf[rt][jh * 4 + j][reg] = (__bf16)(kc[rt][j][reg] + bqv);
        }
    }

    // ================= pass 1: scores / exp per modality =================
    for (int m = 0; m < NMOD; ++m) {
        __syncthreads();                       // all reads of tile done
        stage(lat + ((size_t)row0 * NMOD + m) * DDIM, NMOD * DDIM);
        __syncthreads();

        // bias fold: p = sum_col q[row][col]*bk[m][col] over this lane's cols
        float bkv[8];
        #pragma unroll
        for (int jj = 0; jj < 8; ++jj)
            bkv[jj] = bk[m * DDIM + wc * 128 + jj * 16 + c];
        float p[2][4];
        #pragma unroll
        for (int rt = 0; rt < 2; ++rt)
            #pragma unroll
            for (int reg = 0; reg < 4; ++reg) {
                float t = 0.f;
                #pragma unroll
                for (int jj = 0; jj < 8; ++jj)
                    t += (float)qbf[rt][jj][reg] * bkv[jj];
                p[rt][reg] = t;
            }

        #pragma unroll
        for (int jh = 0; jh < 2; ++jh) {
            f32x4 kc[2][4];
            gemm_half(Wk + (size_t)m * DDIM * DDIM, jh, kc);
            #pragma unroll
            for (int rt = 0; rt < 2; ++rt)
                #pragma unroll
                for (int reg = 0; reg < 4; ++reg) {
                    float t = p[rt][reg];
                    #pragma unroll
                    for (int j = 0; j < 4; ++j)
                        t += (float)qbf[rt][jh * 4 + j][reg] * kc[rt][j][reg];
                    p[rt][reg] = t;
                }
        }

        // reduce over the 16 c-lanes (cols), then across wc via LDS
        #pragma unroll
        for (int mask = 1; mask < 16; mask <<= 1)
            #pragma unroll
            for (int rt = 0; rt < 2; ++rt)
                #pragma unroll
                for (int reg = 0; reg < 4; ++reg)
                    p[rt][reg] += __shfl_xor(p[rt][reg], mask, 64);
        if (c == 0) {
            #pragma unroll
            for (int rt = 0; rt < 2; ++rt)
                #pragma unroll
                for (int reg = 0; reg < 4; ++reg)
                    s_part[wc][wr * 32 + rt * 16 + g * 4 + reg] = p[rt][reg];
        }
        __syncthreads();
        if (tid < BN) {
            float s = s_part[0][tid] + s_part[1][tid]
                    + s_part[2][tid] + s_part[3][tid];
            // scores ~ N(0,1): exp without max-subtraction is safe in fp32
            e_save[tid][m] = __expf(s * 0.044194173824159216f);  // 1/sqrt(512)
        }
        // next loop-top barrier (or post-loop barrier) protects s_part/e_save
    }
    __syncthreads();

    // ======== pass 2: fused = sum_m e_m L_m / Z (own-row layout) ========
    const int r2 = tid >> 3, k2 = tid & 7;     // thread owns row r2, f4 slots k2+8i
    if (r2 < vrows) {
        float e0 = e_save[r2][0], e1 = e_save[r2][1],
              e2 = e_save[r2][2], e3 = e_save[r2][3];
        float iz = 1.0f / (e0 + e1 + e2 + e3);
        f32x4 O[16];
        #pragma unroll
        for (int i = 0; i < 16; ++i) O[i] = (f32x4){0.f, 0.f, 0.f, 0.f};
        const size_t nbase = (size_t)(row0 + r2) * NMOD;
        #pragma unroll
        for (int m = 0; m < NMOD; ++m) {
            float em = e_save[r2][m];
            const float* lp = lat + (nbase + m) * DDIM;
            #pragma unroll
            for (int bat = 0; bat < 2; ++bat) {
                f32x4 tmp[8];
                #pragma unroll
                for (int i = 0; i < 8; ++i)
                    tmp[i] = __builtin_nontemporal_load(
                        (const f32x4*)(lp + (k2 + (bat * 8 + i) * 8) * 4));
                #pragma unroll
                for (int i = 0; i < 8; ++i)
                    O[bat * 8 + i] += em * tmp[i];
            }
        }
        float* op = out + (size_t)(row0 + r2) * DDIM;
        #pragma unroll
        for (int i = 0; i < 16; ++i) {
            f32x4 v = O[i] * iz;   // lanes 0..7 -> 128B contiguous line
            __builtin_nontemporal_store(v, (f32x4*)(op + (k2 + i * 8) * 4));
        }
    }
    if (tid < BN && row0 + tid < NTOK) {
        float e0 = e_save[tid][0], e1 = e_save[tid][1],
              e2 = e_save[tid][2], e3 = e_save[tid][3];
        float iz = 1.0f / (e0 + e1 + e2 + e3);
        f32x4 wv = { e0 * iz, e1 * iz, e2 * iz, e3 * iz };
        __builtin_nontemporal_store(wv,
            (f32x4*)(out + (size_t)NTOK * DDIM + (size_t)(row0 + tid) * 4));
    }
}

extern "C" void kernel_launch(void* const* d_in, const int* in_sizes, int n_in,
                              void* d_out, int out_size, void* d_ws, size_t ws_size,
                              hipStream_t stream)
{
    const float* gnn = (const float*)d_in[0];   // [N, D]
    const float* lat = (const float*)d_in[1];   // [N, M, D]
    const float* Wq  = (const float*)d_in[2];   // [D, D]
    const float* bq  = (const float*)d_in[3];   // [D]
    const float* Wk  = (const float*)d_in[4];   // [M, D, D]
    const float* bk  = (const float*)d_in[5];   // [M, D]
    float* out = (float*)d_out;                 // fused [N,D] ++ weights [N,M]

    hipLaunchKernelGGL(fusion_kernel, dim3(NBLK), dim3(NTHR), 0, stream,
                       gnn, lat, Wq, bq, Wk, bk, out);
}

// Round 4
// 1350.347 us; speedup vs baseline: 1.0895x; 1.0895x over previous
//
#include <hip/hip_runtime.h>

// ---------------------------------------------------------------------------
// InterpretableFusion v4 — algebraic restructure:
//   scores[n,m] = q.k/sqrt(D) = ( x.(G_m l) + x.v_m + l.u_m + c_m )/sqrt(D)
//   where G_m = Wq^T Wk_m  (bf16, 2 MB total -> fits each XCD's 4 MB L2;
//   replaces 5.25 MB fp32 W that thrashed L2 -> L3 latency on MFMA path),
//   v_m = Wq^T bk_m, u_m = Wk_m^T bq, c_m = bq.bk_m  (zero for this input,
//   computed anyway for correctness generality).
// Eliminates the Q-GEMM entirely (-20% MFMA).
// Kernel chain (same-stream, scratch lives in d_out's fused region which
// kernel D fully overwrites; NO d_ws — round-1 failure attributed to d_ws
// OOB; every kernel rewrites all its outputs from d_in each call):
//   A: G_m = Wq^T Wk_m in fp32 VALU, stored bf16 at out[0..524288)
//   A2: u,v,c at out[600000/610000/620000)
//   B: per-64-row block: stage X (bf16 swizzled LDS) -> xbf regs; per m:
//      stage L_m -> z = L@G_m^T (MFMA, j-half split, VGPR<=128, 2 blk/CU)
//      -> dot with xbf + bias folds -> shfl/LDS reduce -> raw scores;
//      softmax -> weights to out[WOFF..)
//   D: fused = sum_m w_m L_m, streaming, coalesced f32x4 nt stores
// ---------------------------------------------------------------------------

typedef __bf16 bf16x8 __attribute__((ext_vector_type(8)));
typedef __bf16 bf16x4 __attribute__((ext_vector_type(4)));
typedef float  f32x4  __attribute__((ext_vector_type(4)));

#define NTOK 50000
#define DDIM 512
#define NMOD 4
#define BN   64
#define NBLK ((NTOK + BN - 1) / BN)        // 782
#define WOFF ((size_t)NTOK * DDIM)         // weights region (float offset)
#define UOFF 600000                        // u[m][d]  (4*512 floats)
#define VOFF 610000                        // v[m][d]
#define COFF 620000                        // c[m]
#define SCALE 0.044194173824159216f        // 1/sqrt(512)

// row stride 1024B (512 bf16); XOR byte bits 4-6 with row&7 (guide §6 G4)
#define SWZ(r, b) ((((r) * 1024) + (b)) ^ (((r) & 7) << 4))

// ============ kernel A: G[m][d][d'] = sum_e Wq[e][d]*Wk[m][e][d'] ============
__global__ __launch_bounds__(256) void g_kernel(
    const float* __restrict__ Wq, const float* __restrict__ Wk,
    float* __restrict__ out)
{
    __shared__ float ldsQ[64 * 64];    // [e][d]
    __shared__ float ldsK[64 * 128];   // [e][d']
    const int tid = threadIdx.x;
    const int b = blockIdx.x;                       // 128 blocks
    const int m = b >> 5, dblk = (b >> 2) & 7, dpb = b & 3;
    const int dloc = tid & 63, q = tid >> 6;
    f32x4 ac[8];
    #pragma unroll
    for (int i = 0; i < 8; ++i) ac[i] = (f32x4){0.f, 0.f, 0.f, 0.f};
    for (int e0 = 0; e0 < DDIM; e0 += 64) {
        __syncthreads();
        #pragma unroll
        for (int it = 0; it < 4; ++it) {
            int idx = it * 256 + tid, e = idx >> 4, c4 = idx & 15;
            *(f32x4*)&ldsQ[e * 64 + c4 * 4] =
                *(const f32x4*)&Wq[(size_t)(e0 + e) * DDIM + dblk * 64 + c4 * 4];
        }
        #pragma unroll
        for (int it = 0; it < 8; ++it) {
            int idx = it * 256 + tid, e = idx >> 5, c4 = idx & 31;
            *(f32x4*)&ldsK[e * 128 + c4 * 4] =
                *(const f32x4*)&Wk[((size_t)m * DDIM + e0 + e) * DDIM + dpb * 128 + c4 * 4];
        }
        __syncthreads();
        for (int e = 0; e < 64; ++e) {
            float wq = ldsQ[e * 64 + dloc];
            const f32x4* wk = (const f32x4*)&ldsK[e * 128 + q * 32];
            #pragma unroll
            for (int i = 0; i < 8; ++i) ac[i] += wq * wk[i];
        }
    }
    __bf16* Gb = (__bf16*)out;
    size_t base = ((size_t)m * DDIM + dblk * 64 + dloc) * DDIM + dpb * 128 + q * 32;
    #pragma unroll
    for (int i = 0; i < 8; ++i) {
        bf16x4 o;
        o[0] = (__bf16)ac[i][0]; o[1] = (__bf16)ac[i][1];
        o[2] = (__bf16)ac[i][2]; o[3] = (__bf16)ac[i][3];
        *(bf16x4*)(Gb + base + i * 4) = o;
    }
}

// ============ kernel A2: u_m = Wk_m^T bq, v_m = Wq^T bk_m, c_m = bq.bk_m =====
__global__ __launch_bounds__(64) void uvc_kernel(
    const float* __restrict__ Wq, const float* __restrict__ bq,
    const float* __restrict__ Wk, const float* __restrict__ bk,
    float* __restrict__ out)
{
    const int b = blockIdx.x;                 // 2048
    const int m = b >> 9, d = b & 511;
    const int lane = threadIdx.x;
    float up = 0.f, vp = 0.f;
    #pragma unroll
    for (int i = 0; i < 8; ++i) {
        int e = lane * 8 + i;
        up += Wk[((size_t)m * DDIM + e) * DDIM + d] * bq[e];
        vp += Wq[(size_t)e * DDIM + d] * bk[m * DDIM + e];
    }
    #pragma unroll
    for (int msk = 1; msk < 64; msk <<= 1) {
        up += __shfl_xor(up, msk, 64);
        vp += __shfl_xor(vp, msk, 64);
    }
    if (lane == 0) {
        out[UOFF + m * DDIM + d] = up;
        out[VOFF + m * DDIM + d] = vp;
    }
    if (d == 0) {
        float cp = 0.f;
        #pragma unroll
        for (int i = 0; i < 8; ++i) {
            int e = lane * 8 + i;
            cp += bq[e] * bk[m * DDIM + e];
        }
        #pragma unroll
        for (int msk = 1; msk < 64; msk <<= 1) cp += __shfl_xor(cp, msk, 64);
        if (lane == 0) out[COFF + m] = cp;
    }
}

// ============ kernel B: scores -> softmax -> weights ============
__global__ __launch_bounds__(512, 4) void scores_kernel(
    const float* __restrict__ gnn, const float* __restrict__ lat,
    float* __restrict__ out)
{
    __shared__ __bf16 tile[BN * DDIM];     // 64 KiB (X once, then L_m)
    __shared__ float  s_part[8][BN];       // 2 KiB
    __shared__ float  s_all[BN][NMOD];     // 1 KiB
    const __bf16* Gb = (const __bf16*)out;

    const int tid = threadIdx.x, lane = tid & 63, w = tid >> 6;
    const int g = (lane >> 4) & 3, c = lane & 15;
    const int row0 = blockIdx.x * BN;
    const int vrows = (NTOK - row0 < BN) ? (NTOK - row0) : BN;

    auto stage = [&](const float* src, int rsF) {
        #pragma unroll
        for (int bat = 0; bat < 2; ++bat) {
            f32x4 tmp[8];
            #pragma unroll
            for (int i = 0; i < 8; ++i) {
                int f4 = (bat * 8 + i) * 512 + tid, r = f4 >> 7, c4 = f4 & 127;
                tmp[i] = (r < vrows)
                    ? __builtin_nontemporal_load(
                          (const f32x4*)(src + (size_t)r * rsF + c4 * 4))
                    : (f32x4){0.f, 0.f, 0.f, 0.f};
            }
            #pragma unroll
            for (int i = 0; i < 8; ++i) {
                int f4 = (bat * 8 + i) * 512 + tid, r = f4 >> 7, c4 = f4 & 127;
                bf16x4 o;
                o[0] = (__bf16)tmp[i][0]; o[1] = (__bf16)tmp[i][1];
                o[2] = (__bf16)tmp[i][2]; o[3] = (__bf16)tmp[i][3];
                *(bf16x4*)((char*)tile + SWZ(r, c4 * 8)) = o;
            }
        }
    };

    // ---- X tile -> xbf regs (acc-layout: rows rt*16+g*4+reg, cols w*64+j*16+c)
    stage(gnn + (size_t)row0 * DDIM, DDIM);
    __syncthreads();
    bf16x4 xbf[4][4];
    #pragma unroll
    for (int rt = 0; rt < 4; ++rt)
        #pragma unroll
        for (int j = 0; j < 4; ++j) {
            bf16x4 t;
            #pragma unroll
            for (int reg = 0; reg < 4; ++reg) {
                int r = rt * 16 + g * 4 + reg, col = w * 64 + j * 16 + c;
                t[reg] = *(const __bf16*)((const char*)tile + SWZ(r, col * 2));
            }
            xbf[rt][j] = t;
        }

    for (int m = 0; m < NMOD; ++m) {
        __syncthreads();   // xbf-extract / prev-m reads of tile & s_part done
        stage(lat + ((size_t)row0 * NMOD + m) * DDIM, NMOD * DDIM);
        __syncthreads();

        // bias folds: p = sum_j x*v + l*u  (zero for this input, kept general)
        float u4[4], v4[4];
        #pragma unroll
        for (int j = 0; j < 4; ++j) {
            int col = w * 64 + j * 16 + c;
            u4[j] = out[UOFF + m * DDIM + col];
            v4[j] = out[VOFF + m * DDIM + col];
        }
        float p[4][4];
        #pragma unroll
        for (int rt = 0; rt < 4; ++rt)
            #pragma unroll
            for (int reg = 0; reg < 4; ++reg) {
                int r = rt * 16 + g * 4 + reg;
                float t = 0.f;
                #pragma unroll
                for (int j = 0; j < 4; ++j) {
                    int col = w * 64 + j * 16 + c;
                    float lv = (float)*(const __bf16*)((const char*)tile +
                                                       SWZ(r, col * 2));
                    t += (float)xbf[rt][j][reg] * v4[j] + lv * u4[j];
                }
                p[rt][reg] = t;
            }

        // z = L @ G_m^T in two j-halves (keeps kacc at 32 VGPRs)
        #pragma unroll
        for (int jh = 0; jh < 2; ++jh) {
            f32x4 kacc[4][2];
            #pragma unroll
            for (int rt = 0; rt < 4; ++rt) {
                kacc[rt][0] = (f32x4){0.f, 0.f, 0.f, 0.f};
                kacc[rt][1] = (f32x4){0.f, 0.f, 0.f, 0.f};
            }
            for (int k0 = 0; k0 < DDIM; k0 += 32) {
                bf16x8 a[4], b[2];
                const int kb = k0 * 2 + g * 16;
                #pragma unroll
                for (int rt = 0; rt < 4; ++rt)
                    a[rt] = *(const bf16x8*)((const char*)tile +
                                             SWZ(rt * 16 + c, kb));
                #pragma unroll
                for (int j2 = 0; j2 < 2; ++j2) {
                    int dcol = w * 64 + (jh * 2 + j2) * 16 + c;
                    b[j2] = *(const bf16x8*)(Gb + ((size_t)m * DDIM + dcol) * DDIM
                                             + k0 + g * 8);
                }
                #pragma unroll
                for (int rt = 0; rt < 4; ++rt)
                    #pragma unroll
                    for (int j2 = 0; j2 < 2; ++j2)
                        kacc[rt][j2] = __builtin_amdgcn_mfma_f32_16x16x32_bf16(
                            a[rt], b[j2], kacc[rt][j2], 0, 0, 0);
            }
            #pragma unroll
            for (int rt = 0; rt < 4; ++rt)
                #pragma unroll
                for (int reg = 0; reg < 4; ++reg) {
                    float t = p[rt][reg];
                    #pragma unroll
                    for (int j2 = 0; j2 < 2; ++j2)
                        t += (float)xbf[rt][jh * 2 + j2][reg] * kacc[rt][j2][reg];
                    p[rt][reg] = t;
                }
        }

        // reduce over 16 c-lanes, then across 8 waves via LDS
        #pragma unroll
        for (int msk = 1; msk < 16; msk <<= 1)
            #pragma unroll
            for (int rt = 0; rt < 4; ++rt)
                #pragma unroll
                for (int reg = 0; reg < 4; ++reg)
                    p[rt][reg] += __shfl_xor(p[rt][reg], msk, 64);
        if (c == 0) {
            #pragma unroll
            for (int rt = 0; rt < 4; ++rt)
                #pragma unroll
                for (int reg = 0; reg < 4; ++reg)
                    s_part[w][rt * 16 + g * 4 + reg] = p[rt][reg];
        }
        __syncthreads();
        if (tid < BN) {
            float s = 0.f;
            #pragma unroll
            for (int ww = 0; ww < 8; ++ww) s += s_part[ww][tid];
            s_all[tid][m] = s + out[COFF + m];
        }
    }

    if (tid < BN && row0 + tid < NTOK) {
        float e0 = __expf(s_all[tid][0] * SCALE), e1 = __expf(s_all[tid][1] * SCALE),
              e2 = __expf(s_all[tid][2] * SCALE), e3 = __expf(s_all[tid][3] * SCALE);
        float iz = 1.f / (e0 + e1 + e2 + e3);
        f32x4 wv = {e0 * iz, e1 * iz, e2 * iz, e3 * iz};
        __builtin_nontemporal_store(wv,
            (f32x4*)(out + WOFF + (size_t)(row0 + tid) * 4));
    }
}

// ============ kernel D: fused = sum_m w_m L_m (pure streaming) ============
__global__ __launch_bounds__(256) void fuse_kernel(
    const float* __restrict__ lat, float* __restrict__ out)
{
    const int tid = threadIdx.x;
    const int rl = tid >> 3, k2 = tid & 7;      // 32 rows/block, 8 thr/row
    const int n = blockIdx.x * 32 + rl;
    if (n >= NTOK) return;
    f32x4 w4 = *(const f32x4*)(out + WOFF + (size_t)n * 4);
    const float* lp0 = lat + (size_t)n * NMOD * DDIM + k2 * 64;
    float* op = out + (size_t)n * DDIM + k2 * 64;
    #pragma unroll
    for (int cc = 0; cc < 4; ++cc) {
        f32x4 ac[4];
        #pragma unroll
        for (int i = 0; i < 4; ++i) ac[i] = (f32x4){0.f, 0.f, 0.f, 0.f};
        #pragma unroll
        for (int m = 0; m < NMOD; ++m) {
            const float* lp = lp0 + m * DDIM + cc * 16;
            #pragma unroll
            for (int i = 0; i < 4; ++i) {
                f32x4 v = __builtin_nontemporal_load((const f32x4*)(lp + i * 4));
                ac[i] += w4[m] * v;
            }
        }
        #pragma unroll
        for (int i = 0; i < 4; ++i)
            __builtin_nontemporal_store(ac[i], (f32x4*)(op + cc * 16 + i * 4));
    }
}

extern "C" void kernel_launch(void* const* d_in, const int* in_sizes, int n_in,
                              void* d_out, int out_size, void* d_ws, size_t ws_size,
                              hipStream_t stream)
{
    const float* gnn = (const float*)d_in[0];   // [N, D]
    const float* lat = (const float*)d_in[1];   // [N, M, D]
    const float* Wq  = (const float*)d_in[2];   // [D, D]
    const float* bq  = (const float*)d_in[3];   // [D]
    const float* Wk  = (const float*)d_in[4];   // [M, D, D]
    const float* bk  = (const float*)d_in[5];   // [M, D]
    float* out = (float*)d_out;                 // fused [N,D] ++ weights [N,M]

    hipLaunchKernelGGL(g_kernel,      dim3(128),  dim3(256), 0, stream, Wq, Wk, out);
    hipLaunchKernelGGL(uvc_kernel,    dim3(2048), dim3(64),  0, stream, Wq, bq, Wk, bk, out);
    hipLaunchKernelGGL(scores_kernel, dim3(NBLK), dim3(512), 0, stream, gnn, lat, out);
    hipLaunchKernelGGL(fuse_kernel,   dim3((NTOK + 31) / 32), dim3(256), 0, stream, lat, out);
}

// Round 7
// 1256.017 us; speedup vs baseline: 1.1713x; 1.0751x over previous
//
#include <hip/hip_runtime.h>
#include <hip/hip_cooperative_groups.h>

namespace cg = cooperative_groups;

// ---------------------------------------------------------------------------
// InterpretableFusion v7 — ONE cooperative kernel, 3 phases, grid.sync between.
//   scores[n,m] = ( x.(G_m l) + x.v_m + l.u_m + c_m )/sqrt(D)
//   G_m = Wq^T Wk_m (bf16, 2 MB, XCD-L2-resident in phase 2).
// Rationale: v1/v6 multi-kernel chains flaked POST-TIMING (stale cross-node
// reads; per-XCD L2 non-coherence under graph replay). All cross-block data
// flow now crosses cg::grid().sync() device-scope fences inside a single
// dispatch — the documented-correct mechanism (guide §1/§6 G16).
// Phase 1: G (256 blocks, 64x64 tiles each) + u,v,c        -> out scratch
// Phase 2: persistent blocks sweep 782 tiles: stage X/L (bf16 swizzled LDS),
//          z = G_m l via MFMA, dot with x, reduce, softmax -> weights
// Phase 3: fused = sum_m w_m L_m (streaming, overwrites G scratch region —
//          dead after sync #2)
// ---------------------------------------------------------------------------

typedef __bf16 bf16x8 __attribute__((ext_vector_type(8)));
typedef __bf16 bf16x4 __attribute__((ext_vector_type(4)));
typedef float  f32x4  __attribute__((ext_vector_type(4)));

#define NTOK 50000
#define DDIM 512
#define NMOD 4
#define BN   64
#define NBLK ((NTOK + BN - 1) / BN)        // 782
#define GRID 256
#define WOFF ((size_t)NTOK * DDIM)         // weights region (float offset)
#define UOFF 600000                        // u[m][d]
#define VOFF 610000                        // v[m][d]
#define COFF 620000                        // c[m]
#define SCALE 0.044194173824159216f        // 1/sqrt(512)

// row stride 1024B (512 bf16); XOR byte bits 4-6 with row&7 (guide §6 G4)
#define SWZ(r, b) ((((r) * 1024) + (b)) ^ (((r) & 7) << 4))

__global__ __launch_bounds__(512, 2) void mono_kernel(
    const float* __restrict__ gnn, const float* __restrict__ lat,
    const float* __restrict__ Wq, const float* __restrict__ bq,
    const float* __restrict__ Wk, const float* __restrict__ bk,
    float* __restrict__ out)
{
    __shared__ __align__(16) char smem[68608];
    const int tid = threadIdx.x;
    const int bid = blockIdx.x;
    cg::grid_group grid = cg::this_grid();

    // ================= phase 1: G = Wq^T Wk_m  (+ u, v, c) =================
    {
        float* ldsQ = (float*)smem;            // [64][64]
        float* ldsK = (float*)(smem + 16384);  // [64][64]
        const int m = bid >> 6, ib = bid & 63, dblk = ib >> 3, dpb = ib & 7;
        const int dl = tid >> 3, c8 = tid & 7; // row-in-tile, col-group(8)
        f32x4 ac0 = {0.f,0.f,0.f,0.f}, ac1 = {0.f,0.f,0.f,0.f};
        for (int e0 = 0; e0 < DDIM; e0 += 64) {
            __syncthreads();
            #pragma unroll
            for (int it = 0; it < 2; ++it) {
                int idx = it * 512 + tid, e = idx >> 4, c4 = idx & 15;
                *(f32x4*)&ldsQ[e * 64 + c4 * 4] =
                    *(const f32x4*)&Wq[(size_t)(e0 + e) * DDIM + dblk * 64 + c4 * 4];
                *(f32x4*)&ldsK[e * 64 + c4 * 4] =
                    *(const f32x4*)&Wk[((size_t)m * DDIM + e0 + e) * DDIM + dpb * 64 + c4 * 4];
            }
            __syncthreads();
            for (int e = 0; e < 64; ++e) {
                float wq = ldsQ[e * 64 + dl];
                const f32x4* wk = (const f32x4*)&ldsK[e * 64 + c8 * 8];
                ac0 += wq * wk[0];
                ac1 += wq * wk[1];
            }
        }
        __bf16* Gb = (__bf16*)out;
        bf16x8 o;
        o[0]=(__bf16)ac0[0]; o[1]=(__bf16)ac0[1]; o[2]=(__bf16)ac0[2]; o[3]=(__bf16)ac0[3];
        o[4]=(__bf16)ac1[0]; o[5]=(__bf16)ac1[1]; o[6]=(__bf16)ac1[2]; o[7]=(__bf16)ac1[3];
        *(bf16x8*)(Gb + ((size_t)m * DDIM + dblk * 64 + dl) * DDIM + dpb * 64 + c8 * 8) = o;

        if (bid < 32) {                        // u, v, c on 32 blocks
            __syncthreads();                   // LDS G-reads done; reuse buffer
            float* up = ldsQ;                  // [4][64]
            float* vp = ldsQ + 256;            // [4][64]
            const int m2 = bid >> 3, dc = bid & 7;
            if (tid < 256) {
                const int dl2 = tid & 63, eg = tid >> 6;
                const int d = dc * 64 + dl2;
                float us = 0.f, vs = 0.f;
                #pragma unroll 4
                for (int e = eg * 128; e < eg * 128 + 128; ++e) {
                    us += Wk[((size_t)m2 * DDIM + e) * DDIM + d] * bq[e];
                    vs += Wq[(size_t)e * DDIM + d] * bk[m2 * DDIM + e];
                }
                up[eg * 64 + dl2] = us; vp[eg * 64 + dl2] = vs;
            }
            __syncthreads();
            if (tid < 64) {
                const int d = dc * 64 + tid;
                out[UOFF + m2 * DDIM + d] = up[tid] + up[64+tid] + up[128+tid] + up[192+tid];
                out[VOFF + m2 * DDIM + d] = vp[tid] + vp[64+tid] + vp[128+tid] + vp[192+tid];
                if (dc == 0) {
                    float cp = 0.f;
                    #pragma unroll
                    for (int i = 0; i < 8; ++i)
                        cp += bq[tid * 8 + i] * bk[m2 * DDIM + tid * 8 + i];
                    #pragma unroll
                    for (int msk = 1; msk < 64; msk <<= 1)
                        cp += __shfl_xor(cp, msk, 64);
                    if (tid == 0) out[COFF + m2] = cp;
                }
            }
        }
    }
    grid.sync();   // G/u/v/c visible device-wide

    // ================= phase 2: scores -> softmax -> weights =================
    {
        __bf16* tile  = (__bf16*)smem;             // 64 KiB
        float* s_part = (float*)(smem + 65536);    // [8][64]
        float* s_all  = (float*)(smem + 67584);    // [64][4]
        const __bf16* Gb = (const __bf16*)out;
        const int lane = tid & 63, w = tid >> 6;
        const int g = (lane >> 4) & 3, c = lane & 15;

        for (int t = bid; t < NBLK; t += GRID) {
            const int row0 = t * BN;
            const int vrows = (NTOK - row0 < BN) ? (NTOK - row0) : BN;

            auto stage = [&](const float* src, int rsF) {
                #pragma unroll
                for (int bat = 0; bat < 2; ++bat) {
                    f32x4 tmp[8];
                    #pragma unroll
                    for (int i = 0; i < 8; ++i) {
                        int f4 = (bat * 8 + i) * 512 + tid, r = f4 >> 7, c4 = f4 & 127;
                        tmp[i] = (r < vrows)
                            ? __builtin_nontemporal_load(
                                  (const f32x4*)(src + (size_t)r * rsF + c4 * 4))
                            : (f32x4){0.f, 0.f, 0.f, 0.f};
                    }
                    #pragma unroll
                    for (int i = 0; i < 8; ++i) {
                        int f4 = (bat * 8 + i) * 512 + tid, r = f4 >> 7, c4 = f4 & 127;
                        bf16x4 o;
                        o[0] = (__bf16)tmp[i][0]; o[1] = (__bf16)tmp[i][1];
                        o[2] = (__bf16)tmp[i][2]; o[3] = (__bf16)tmp[i][3];
                        *(bf16x4*)((char*)tile + SWZ(r, c4 * 8)) = o;
                    }
                }
            };

            // X tile -> xbf regs (rows rt*16+g*4+reg, cols w*64+j*16+c)
            stage(gnn + (size_t)row0 * DDIM, DDIM);
            __syncthreads();
            bf16x4 xbf[4][4];
            #pragma unroll
            for (int rt = 0; rt < 4; ++rt)
                #pragma unroll
                for (int j = 0; j < 4; ++j) {
                    bf16x4 tq;
                    #pragma unroll
                    for (int reg = 0; reg < 4; ++reg) {
                        int r = rt * 16 + g * 4 + reg, col = w * 64 + j * 16 + c;
                        tq[reg] = *(const __bf16*)((const char*)tile + SWZ(r, col * 2));
                    }
                    xbf[rt][j] = tq;
                }

            for (int m = 0; m < NMOD; ++m) {
                __syncthreads();
                stage(lat + ((size_t)row0 * NMOD + m) * DDIM, NMOD * DDIM);
                __syncthreads();

                float u4[4], v4[4];
                #pragma unroll
                for (int j = 0; j < 4; ++j) {
                    int col = w * 64 + j * 16 + c;
                    u4[j] = out[UOFF + m * DDIM + col];
                    v4[j] = out[VOFF + m * DDIM + col];
                }
                float p[4][4];
                #pragma unroll
                for (int rt = 0; rt < 4; ++rt)
                    #pragma unroll
                    for (int reg = 0; reg < 4; ++reg) {
                        int r = rt * 16 + g * 4 + reg;
                        float tacc = 0.f;
                        #pragma unroll
                        for (int j = 0; j < 4; ++j) {
                            int col = w * 64 + j * 16 + c;
                            float lv = (float)*(const __bf16*)((const char*)tile +
                                                               SWZ(r, col * 2));
                            tacc += (float)xbf[rt][j][reg] * v4[j] + lv * u4[j];
                        }
                        p[rt][reg] = tacc;
                    }

                // z = G_m l via MFMA in two j-halves (kacc stays at 32 VGPRs)
                #pragma unroll
                for (int jh = 0; jh < 2; ++jh) {
                    f32x4 kacc[4][2];
                    #pragma unroll
                    for (int rt = 0; rt < 4; ++rt) {
                        kacc[rt][0] = (f32x4){0.f, 0.f, 0.f, 0.f};
                        kacc[rt][1] = (f32x4){0.f, 0.f, 0.f, 0.f};
                    }
                    for (int k0 = 0; k0 < DDIM; k0 += 32) {
                        bf16x8 a[4], b[2];
                        const int kb = k0 * 2 + g * 16;
                        #pragma unroll
                        for (int rt = 0; rt < 4; ++rt)
                            a[rt] = *(const bf16x8*)((const char*)tile +
                                                     SWZ(rt * 16 + c, kb));
                        #pragma unroll
                        for (int j2 = 0; j2 < 2; ++j2) {
                            int dcol = w * 64 + (jh * 2 + j2) * 16 + c;
                            b[j2] = *(const bf16x8*)(Gb + ((size_t)m * DDIM + dcol) * DDIM
                                                     + k0 + g * 8);
                        }
                        #pragma unroll
                        for (int rt = 0; rt < 4; ++rt)
                            #pragma unroll
                            for (int j2 = 0; j2 < 2; ++j2)
                                kacc[rt][j2] = __builtin_amdgcn_mfma_f32_16x16x32_bf16(
                                    a[rt], b[j2], kacc[rt][j2], 0, 0, 0);
                    }
                    #pragma unroll
                    for (int rt = 0; rt < 4; ++rt)
                        #pragma unroll
                        for (int reg = 0; reg < 4; ++reg) {
                            float tacc = p[rt][reg];
                            #pragma unroll
                            for (int j2 = 0; j2 < 2; ++j2)
                                tacc += (float)xbf[rt][jh * 2 + j2][reg] * kacc[rt][j2][reg];
                            p[rt][reg] = tacc;
                        }
                }

                // reduce over 16 c-lanes, then across 8 waves via LDS
                #pragma unroll
                for (int msk = 1; msk < 16; msk <<= 1)
                    #pragma unroll
                    for (int rt = 0; rt < 4; ++rt)
                        #pragma unroll
                        for (int reg = 0; reg < 4; ++reg)
                            p[rt][reg] += __shfl_xor(p[rt][reg], msk, 64);
                if (c == 0) {
                    #pragma unroll
                    for (int rt = 0; rt < 4; ++rt)
                        #pragma unroll
                        for (int reg = 0; reg < 4; ++reg)
                            s_part[w * 64 + rt * 16 + g * 4 + reg] = p[rt][reg];
                }
                __syncthreads();
                if (tid < BN) {
                    float s = 0.f;
                    #pragma unroll
                    for (int ww = 0; ww < 8; ++ww) s += s_part[ww * 64 + tid];
                    s_all[tid * 4 + m] = s + out[COFF + m];
                }
            }

            if (tid < BN && row0 + tid < NTOK) {
                float e0 = __expf(s_all[tid*4+0] * SCALE), e1 = __expf(s_all[tid*4+1] * SCALE),
                      e2 = __expf(s_all[tid*4+2] * SCALE), e3 = __expf(s_all[tid*4+3] * SCALE);
                float iz = 1.f / (e0 + e1 + e2 + e3);
                f32x4 wv = {e0 * iz, e1 * iz, e2 * iz, e3 * iz};
                *(f32x4*)(out + WOFF + (size_t)(row0 + tid) * 4) = wv;   // regular store
            }
        }
    }
    grid.sync();   // weights visible; G region now dead

    // ================= phase 3: fused = sum_m w_m L_m =================
    {
        const int rl = tid >> 3, k2 = tid & 7;     // 64 rows/iter, 8 thr/row
        const int base = bid * 196;                // 256*196 = 50176 >= 50000
        #pragma unroll
        for (int ii = 0; ii < 4; ++ii) {
            const int rr = ii * 64 + rl;
            const int n = base + rr;
            if (rr < 196 && n < NTOK) {
                f32x4 w4 = *(const f32x4*)(out + WOFF + (size_t)n * 4);
                const float* lp0 = lat + (size_t)n * NMOD * DDIM + k2 * 64;
                float* op = out + (size_t)n * DDIM + k2 * 64;
                #pragma unroll
                for (int cc = 0; cc < 4; ++cc) {
                    f32x4 ac[4];
                    #pragma unroll
                    for (int i = 0; i < 4; ++i) ac[i] = (f32x4){0.f, 0.f, 0.f, 0.f};
                    #pragma unroll
                    for (int m = 0; m < NMOD; ++m) {
                        const float* lp = lp0 + m * DDIM + cc * 16;
                        #pragma unroll
                        for (int i = 0; i < 4; ++i) {
                            f32x4 v = __builtin_nontemporal_load((const f32x4*)(lp + i * 4));
                            ac[i] += w4[m] * v;
                        }
                    }
                    #pragma unroll
                    for (int i = 0; i < 4; ++i)
                        __builtin_nontemporal_store(ac[i], (f32x4*)(op + cc * 16 + i * 4));
                }
            }
        }
    }
}

extern "C" void kernel_launch(void* const* d_in, const int* in_sizes, int n_in,
                              void* d_out, int out_size, void* d_ws, size_t ws_size,
                              hipStream_t stream)
{
    const float* gnn = (const float*)d_in[0];   // [N, D]
    const float* lat = (const float*)d_in[1];   // [N, M, D]
    const float* Wq  = (const float*)d_in[2];   // [D, D]
    const float* bq  = (const float*)d_in[3];   // [D]
    const float* Wk  = (const float*)d_in[4];   // [M, D, D]
    const float* bk  = (const float*)d_in[5];   // [M, D]
    float* out = (float*)d_out;                 // fused [N,D] ++ weights [N,M]

    void* args[] = { (void*)&gnn, (void*)&lat, (void*)&Wq, (void*)&bq,
                     (void*)&Wk, (void*)&bk, (void*)&out };
    hipLaunchCooperativeKernel((const void*)mono_kernel, dim3(GRID), dim3(512),
                               args, 0, stream);
}